// Round 1
// 338.383 us; speedup vs baseline: 1.0212x; 1.0212x over previous
//
#include <hip/hip_runtime.h>

// SimpleHashEncoder1D: out[n, l*2+f] = hash_table[floor(xn*scale[l]+0.5) & (T-1)][f]
// xn = (x+bound)/(2*bound), scale[l] = 16*b^l - 1, b = expf((logf(2^19)-logf(16))/15)
//
// float32 bit-exactness (verified R1, absmax == 0.0):
//   b = 0x3FFFFFFF = 2 - 2^-23   (NOT 2.0: correctly-rounded f32 log/exp chain)
//   fl32(b^l) = 2^l * (1 - l*2^-24)            (exact)
//   scale[l]  = (2^(l+4) - 1) - l*2^(l-20)     (exactly representable)
//   bits(scale[l]) = ((130+l)<<23) | (0x800000 - (0x100000>>l) - l)
// Separate mul/add (numpy does not fuse); __fdiv_rn for the normalize.
// Indices provably in [0, 2^19) -> '& (T-1)' == '% T'.
//
// R4 (this round): MLP restructure. rocprof shows the kernel itself is
// <164 us (it doesn't make top-5; the 165 us dispatches are harness poison
// fills) and writes run far below HBM peak -> latency-bound on the 2
// outstanding L2/L3 gathers per thread, not BW-bound. Give each thread 4
// output slots (stride 2^22 preserves j = slot&7): 4 x-loads, then all 8
// table gathers issued back-to-back (4x deeper MLP), then 4 coalesced nt
// stores. Arithmetic identical to R3; pure scheduling change.

constexpr int T_SIZE = 524288;   // 2^19
constexpr int N_PTS  = 2097152;  // 2^21
constexpr int SLOTS  = N_PTS * 8;      // 2^24 float4 output slots
constexpr int KI     = 4;              // slots per thread
constexpr int NTH    = SLOTS / KI;     // 2^22 threads

typedef float vfloat4 __attribute__((ext_vector_type(4)));

__device__ __forceinline__ float scale_for_level(int l) {
    unsigned bits = ((130u + (unsigned)l) << 23)
                  | (0x800000u - (0x100000u >> l) - (unsigned)l);
    return __uint_as_float(bits);
}

__global__ __launch_bounds__(256) void hash_encode_kernel(
    const float* __restrict__ x,
    const float* __restrict__ table,
    const int* __restrict__ bound_p,
    float* __restrict__ out)
{
    int tid = blockIdx.x * 256 + threadIdx.x;   // 2^22 threads

    // NTH is a multiple of 8, so slot (tid + k*NTH) has the same low 3 bits
    // for all k: one level-pair (2j, 2j+1) per thread, scales computed once.
    int j  = tid & 7;
    int l0 = j << 1;
    float s0 = scale_for_level(l0);
    float s1 = scale_for_level(l0 + 1);

    float fb  = (float)bound_p[0];
    float fb2 = __fmul_rn(2.0f, fb);

    // Phase 1: all x loads in flight (streamed once, don't cache)
    float xv[KI];
#pragma unroll
    for (int k = 0; k < KI; ++k) {
        int n = (tid + k * NTH) >> 3;           // point index for slot k
        xv[k] = __builtin_nontemporal_load(&x[n]);
    }

    // Phase 2: indices. xs >= 0.5 always, so int-trunc == floor; result
    // < 2^19 so '&' is exact mod.
    int i0[KI], i1[KI];
#pragma unroll
    for (int k = 0; k < KI; ++k) {
        float xn  = __fdiv_rn(__fadd_rn(xv[k], fb), fb2);
        float xs0 = __fadd_rn(__fmul_rn(xn, s0), 0.5f);
        float xs1 = __fadd_rn(__fmul_rn(xn, s1), 0.5f);
        i0[k] = ((int)xs0) & (T_SIZE - 1);
        i1[k] = ((int)xs1) & (T_SIZE - 1);
    }

    // Phase 3: all 8 gathers back-to-back (cached: table must stay L2-resident)
    const float2* t2 = (const float2*)table;
    float2 a[KI], b[KI];
#pragma unroll
    for (int k = 0; k < KI; ++k) {
        a[k] = t2[i0[k]];
        b[k] = t2[i1[k]];
    }

    // Phase 4: coalesced nt stores (stream past L2, don't evict the table)
#pragma unroll
    for (int k = 0; k < KI; ++k) {
        vfloat4 o;
        o.x = a[k].x; o.y = a[k].y; o.z = b[k].x; o.w = b[k].y;
        __builtin_nontemporal_store(o, (vfloat4*)out + (tid + k * NTH));
    }
}

extern "C" void kernel_launch(void* const* d_in, const int* in_sizes, int n_in,
                              void* d_out, int out_size, void* d_ws, size_t ws_size,
                              hipStream_t stream) {
    const float* x     = (const float*)d_in[0];
    const float* table = (const float*)d_in[1];
    const int*   bound = (const int*)d_in[2];
    float* out = (float*)d_out;

    int blocks = NTH / 256;                    // 16384
    hash_encode_kernel<<<blocks, 256, 0, stream>>>(x, table, bound, out);
}